// Round 9
// baseline (352.877 us; speedup 1.0000x reference)
//
#include <hip/hip_runtime.h>
#include <cstdint>

#define NNODES 100000
#define NEDGES 1600000
#define GCNT 6250        // count blocks   (256 edges each, 6250*256 == NEDGES)
#define GENC 6250        // encode blocks  (1 uint4/thread)
#define GWPK 24          // weight-pack blocks (6144 threads)
#define GSCN 391         // scan blocks    (391*256 >= NNODES)

typedef __attribute__((ext_vector_type(8))) __bf16 bf16x8;
typedef __attribute__((ext_vector_type(4))) float f32x4;
typedef short v2s __attribute__((ext_vector_type(2)));

__device__ __forceinline__ unsigned short f2bf_rne(float f) {
    unsigned int u = __float_as_uint(f);
    u += 0x7fffu + ((u >> 16) & 1u);
    return (unsigned short)(u >> 16);
}
// involutive monotone map: bf16 float order <-> signed i16 order (per packed half)
__device__ __forceinline__ unsigned encdec(unsigned u) {
    return u ^ (((u & 0x80008000u) >> 15) * 0x7FFFu);
}
__device__ __forceinline__ unsigned pkmax(unsigned a, unsigned b) {
    v2s r = __builtin_elementwise_max(__builtin_bit_cast(v2s, a), __builtin_bit_cast(v2s, b));
    return __builtin_bit_cast(unsigned, r);
}
__device__ __forceinline__ uint4 pkmax4(uint4 a, uint4 b) {
    uint4 r;
    r.x = pkmax(a.x, b.x); r.y = pkmax(a.y, b.y);
    r.z = pkmax(a.z, b.z); r.w = pkmax(a.w, b.w);
    return r;
}

// ===== 2-SLICE layout =====
// Feature matrices [N][128] bf16 stored as 2 slices of 64 channels:
//   uint4 index(slice s, node n, j) = ((size_t)s*N + n)*8 + j,  j in [0,8)

// ---------------- K1: count degrees (+edge ordinal) | encode x | pack weights
__global__ __launch_bounds__(256) void prep_kernel(
        const int* __restrict__ src, const int* __restrict__ dst,
        int* __restrict__ degCnt, unsigned short* __restrict__ edgeOrd,
        const float4* __restrict__ xin, uint4* __restrict__ xeout,
        const float* __restrict__ W1l, const float* __restrict__ W1r,
        const float* __restrict__ W2l, const float* __restrict__ W2r,
        uint4* __restrict__ Wf1, uint4* __restrict__ Wf2) {
    if (blockIdx.x < GCNT) {
        // ---- degree count + within-node ordinal (order arbitrary == fine for max)
        int e = blockIdx.x * 256 + threadIdx.x;           // < NEDGES exactly
        int d = dst[e];
        edgeOrd[e] = (unsigned short)atomicAdd(&degCnt[d], 1);
        return;
    }
    if (blockIdx.x < GCNT + GENC) {
        // ---- encode x into sliced layout ----
        int t = (blockIdx.x - GCNT) * 256 + threadIdx.x;  // 0..1.6M-1 sliced uint4 idx
        int s = t / (NNODES * 8);
        int rem = t - s * (NNODES * 8);
        int n = rem >> 3, j = rem & 7;
        int f = n * 32 + s * 16 + j * 2;                  // float4 idx (ch 64s+8j)
        float4 v0 = xin[f], v1 = xin[f + 1];
        uint4 o;
        o.x = encdec((unsigned)f2bf_rne(v0.x) | ((unsigned)f2bf_rne(v0.y) << 16));
        o.y = encdec((unsigned)f2bf_rne(v0.z) | ((unsigned)f2bf_rne(v0.w) << 16));
        o.z = encdec((unsigned)f2bf_rne(v1.x) | ((unsigned)f2bf_rne(v1.y) << 16));
        o.w = encdec((unsigned)f2bf_rne(v1.z) | ((unsigned)f2bf_rne(v1.w) << 16));
        xeout[t] = o;
        return;
    }
    // ---- weight pack (24 blocks) ----
    int t = (blockIdx.x - GCNT - GENC) * 256 + threadIdx.x;   // 0..6143
    unsigned short s[8];
    if (t < 4096) {                           // layer 1: BN=128, NT=8
        int h = t >> 11, kt = (t >> 9) & 3, nt = (t >> 6) & 7, lane = t & 63;
        const float* W = h ? W1r : W1l;
        int k0 = kt * 32 + (lane >> 4) * 8;
        int col = nt * 16 + (lane & 15);
#pragma unroll
        for (int jj = 0; jj < 8; ++jj) s[jj] = f2bf_rne(W[(k0 + jj) * 128 + col]);
        uint4 o;
        o.x = (unsigned)s[0] | ((unsigned)s[1] << 16);
        o.y = (unsigned)s[2] | ((unsigned)s[3] << 16);
        o.z = (unsigned)s[4] | ((unsigned)s[5] << 16);
        o.w = (unsigned)s[6] | ((unsigned)s[7] << 16);
        Wf1[t] = o;
    } else {                                  // layer 2: BN=64, NT=4
        int u = t - 4096;                     // 0..2047
        int h = u >> 10, kt = (u >> 8) & 3, nt = (u >> 6) & 3, lane = u & 63;
        const float* W = h ? W2r : W2l;
        int k0 = kt * 32 + (lane >> 4) * 8;
        int col = nt * 16 + (lane & 15);
#pragma unroll
        for (int jj = 0; jj < 8; ++jj) s[jj] = f2bf_rne(W[(k0 + jj) * 64 + col]);
        uint4 o;
        o.x = (unsigned)s[0] | ((unsigned)s[1] << 16);
        o.y = (unsigned)s[2] | ((unsigned)s[3] << 16);
        o.z = (unsigned)s[4] | ((unsigned)s[5] << 16);
        o.w = (unsigned)s[6] | ((unsigned)s[7] << 16);
        Wf2[u] = o;
    }
}

// ---------------- K2: rowBeg/rowEnd via block scan + global cursor ----------
// Cross-block order is arbitrary (ranges need only be disjoint+contiguous).
__global__ __launch_bounds__(256) void scan_kernel(
        const int* __restrict__ degCnt, int* __restrict__ cursor,
        int* __restrict__ rowBeg, int* __restrict__ rowEnd) {
    __shared__ int cnt[256];
    __shared__ int sbase;
    const int tid = threadIdx.x;
    const int n = blockIdx.x * 256 + tid;
    const int d = (n < NNODES) ? degCnt[n] : 0;
    cnt[tid] = d;
    __syncthreads();
    for (int off = 1; off < 256; off <<= 1) {
        int add = (tid >= off) ? cnt[tid - off] : 0;
        __syncthreads();
        cnt[tid] += add;
        __syncthreads();
    }
    int inc = cnt[tid];                       // inclusive prefix
    if (tid == 255) sbase = atomicAdd(cursor, inc);   // inc(255) == block total
    __syncthreads();
    if (n < NNODES) {
        rowBeg[n] = sbase + inc - d;
        rowEnd[n] = sbase + inc;
    }
}

// ---------------- K3: atomic-free scatter into CSR ---------------------------
__global__ __launch_bounds__(256) void scatter_kernel(
        const int* __restrict__ src, const int* __restrict__ dst,
        const unsigned short* __restrict__ edgeOrd, const int* __restrict__ rowBeg,
        unsigned int* __restrict__ sortedSrc) {
    int e = blockIdx.x * 256 + threadIdx.x;   // < NEDGES exactly
    int d = dst[e];
    sortedSrc[rowBeg[d] + (int)edgeOrd[e]] = (unsigned)src[e];
}

// ---------------- FUSED aggregate + SAGE GEMM (R6-proven structure) ----------
// Block = 16 nodes. Phase 1: 4 waves gather+max (wave = 8 nodes x 1 slice,
// lane k(3b)|j(3b)), 16-deep prologue + masked tail; result -> LDS [16][17].
// Phase 2: one barrier, 16-row MFMA GEMM (agg@Wl + root@Wr), bias(+relu), write.
template<int BN, bool RELU, bool ENCOUT, typename OutT>
__global__ __launch_bounds__(256) void sage_fused(
        const uint4* __restrict__ xsl,          // sliced encoded features
        const int* __restrict__ rowBeg,
        const int* __restrict__ rowEnd,
        const unsigned int* __restrict__ sortedSrc,
        const uint4* __restrict__ Wf,           // fragment-packed weights
        const float* __restrict__ bias,         // [BN] f32
        OutT* __restrict__ C,                   // ENCOUT: sliced bf16; else [M][BN] f32
        int nN) {
    constexpr int NT = BN / 16;                 // packed column tiles (8 or 4)
    constexpr int NTW = BN / 64;                // column tiles per wave (2 or 1)
    __shared__ uint4 lds[16][17];               // +1 pad: row stride 272B
    const int wv   = threadIdx.x >> 6;
    const int lane = threadIdx.x & 63;
    const int n0   = blockIdx.x * 16;           // grid exact: 6250*16 == NNODES

    // ---------- phase 1: aggregation ----------
    {
        const int s  = wv & 1;                  // slice
        const int nh = wv >> 1;                 // node half
        const int k  = lane >> 3;               // node within half
        const int j  = lane & 7;                // uint4 within 128B slice row
        const int kb = k << 3;
        const int n  = n0 + nh * 8 + k;
        const size_t srow = (size_t)s * nN;

        const int beg = rowBeg[n], end = rowEnd[n];
        const int m = end - beg;

        int maxm = m;
        maxm = max(maxm, __shfl_xor(maxm, 8));
        maxm = max(maxm, __shfl_xor(maxm, 16));
        maxm = max(maxm, __shfl_xor(maxm, 32));

        int idv0 = 0, idv1 = 0;
        if (m > 0) {
            idv0 = (int)sortedSrc[min(beg + j,     end - 1)];
            idv1 = (int)sortedSrc[min(beg + 8 + j, end - 1)];
        }
        int a0 = __shfl(idv0, kb | 0), a1 = __shfl(idv0, kb | 1);
        int a2 = __shfl(idv0, kb | 2), a3 = __shfl(idv0, kb | 3);
        int a4 = __shfl(idv0, kb | 4), a5 = __shfl(idv0, kb | 5);
        int a6 = __shfl(idv0, kb | 6), a7 = __shfl(idv0, kb | 7);
        int b0 = __shfl(idv1, kb | 0), b1 = __shfl(idv1, kb | 1);
        int b2 = __shfl(idv1, kb | 2), b3 = __shfl(idv1, kb | 3);
        int b4 = __shfl(idv1, kb | 4), b5 = __shfl(idv1, kb | 5);
        int b6 = __shfl(idv1, kb | 6), b7 = __shfl(idv1, kb | 7);
        uint4 q0  = xsl[(srow + a0) * 8 + j];
        uint4 q1  = xsl[(srow + a1) * 8 + j];
        uint4 q2  = xsl[(srow + a2) * 8 + j];
        uint4 q3  = xsl[(srow + a3) * 8 + j];
        uint4 q4  = xsl[(srow + a4) * 8 + j];
        uint4 q5  = xsl[(srow + a5) * 8 + j];
        uint4 q6  = xsl[(srow + a6) * 8 + j];
        uint4 q7  = xsl[(srow + a7) * 8 + j];
        uint4 q8  = xsl[(srow + b0) * 8 + j];
        uint4 q9  = xsl[(srow + b1) * 8 + j];
        uint4 q10 = xsl[(srow + b2) * 8 + j];
        uint4 q11 = xsl[(srow + b3) * 8 + j];
        uint4 q12 = xsl[(srow + b4) * 8 + j];
        uint4 q13 = xsl[(srow + b5) * 8 + j];
        uint4 q14 = xsl[(srow + b6) * 8 + j];
        uint4 q15 = xsl[(srow + b7) * 8 + j];
        uint4 accA = pkmax4(pkmax4(pkmax4(q0, q1), pkmax4(q2, q3)),
                            pkmax4(pkmax4(q4, q5), pkmax4(q6, q7)));
        uint4 accB = pkmax4(pkmax4(pkmax4(q8, q9), pkmax4(q10, q11)),
                            pkmax4(pkmax4(q12, q13), pkmax4(q14, q15)));
        uint4 acc = pkmax4(accA, accB);

        for (int e0 = 16; e0 < maxm; e0 += 8) {
            if (e0 < m) {
                int idt = (int)sortedSrc[min(beg + e0 + j, end - 1)];
                int t0 = __shfl(idt, kb | 0), t1 = __shfl(idt, kb | 1);
                int t2 = __shfl(idt, kb | 2), t3 = __shfl(idt, kb | 3);
                int t4 = __shfl(idt, kb | 4), t5 = __shfl(idt, kb | 5);
                int t6 = __shfl(idt, kb | 6), t7 = __shfl(idt, kb | 7);
                uint4 u0 = xsl[(srow + t0) * 8 + j];
                uint4 u1 = xsl[(srow + t1) * 8 + j];
                uint4 u2 = xsl[(srow + t2) * 8 + j];
                uint4 u3 = xsl[(srow + t3) * 8 + j];
                uint4 u4 = xsl[(srow + t4) * 8 + j];
                uint4 u5 = xsl[(srow + t5) * 8 + j];
                uint4 u6 = xsl[(srow + t6) * 8 + j];
                uint4 u7 = xsl[(srow + t7) * 8 + j];
                acc = pkmax4(acc, pkmax4(pkmax4(pkmax4(u0, u1), pkmax4(u2, u3)),
                                         pkmax4(pkmax4(u4, u5), pkmax4(u6, u7))));
            }
        }

        uint4 o;
        if (m > 0) { o = acc; }
        else       { o.x = o.y = o.z = o.w = 0u; }   // enc(0)==0
        lds[nh * 8 + k][s * 8 + j] = o;
    }
    __syncthreads();

    // ---------- phase 2: GEMM (16 rows x BN) ----------
    const int quad = lane >> 4;
    const int mrow = lane & 15;
    const int r    = n0 + mrow;                 // root row (always < nN)

    f32x4 acc[NTW];
#pragma unroll
    for (int t = 0; t < NTW; ++t) acc[t] = (f32x4){0.f, 0.f, 0.f, 0.f};

#pragma unroll
    for (int kt = 0; kt < 4; ++kt) {
        const int q = kt * 4 + quad;            // uint4 idx: channels q*8..q*8+7
        uint4 ta = lds[mrow][q];
        uint4 tr = xsl[((size_t)(q >> 3) * nN + r) * 8 + (q & 7)];
        ta.x = encdec(ta.x); ta.y = encdec(ta.y); ta.z = encdec(ta.z); ta.w = encdec(ta.w);
        tr.x = encdec(tr.x); tr.y = encdec(tr.y); tr.z = encdec(tr.z); tr.w = encdec(tr.w);
        bf16x8 aa = __builtin_bit_cast(bf16x8, ta);
        bf16x8 ar = __builtin_bit_cast(bf16x8, tr);
#pragma unroll
        for (int t = 0; t < NTW; ++t) {
            const int ct = wv * NTW + t;        // global column tile
            bf16x8 wb0 = __builtin_bit_cast(bf16x8, Wf[(kt * NT + ct) * 64 + lane]);
            acc[t] = __builtin_amdgcn_mfma_f32_16x16x32_bf16(aa, wb0, acc[t], 0, 0, 0);
            bf16x8 wb1 = __builtin_bit_cast(bf16x8, Wf[((4 + kt) * NT + ct) * 64 + lane]);
            acc[t] = __builtin_amdgcn_mfma_f32_16x16x32_bf16(ar, wb1, acc[t], 0, 0, 0);
        }
    }

    // epilogue: D layout col=mrow (within tile), row=quad*4+reg
#pragma unroll
    for (int t = 0; t < NTW; ++t) {
        const int col = (wv * NTW + t) * 16 + mrow;
        const float bv = bias[col];
#pragma unroll
        for (int rr = 0; rr < 4; ++rr) {
            const int grow = n0 + quad * 4 + rr;
            float v = acc[t][rr] + bv;
            if (RELU) v = fmaxf(v, 0.0f);
            if constexpr (ENCOUT) {
                unsigned u = f2bf_rne(v);
                u ^= ((u >> 15) & 1u) * 0x7FFFu;   // encode for next layer
                // sliced write: slice=col>>6, within-slice ch=col&63
                C[((size_t)(col >> 6) * nN + grow) * 64 + (col & 63)] = (OutT)u;
            } else {
                C[(size_t)grow * BN + col] = (OutT)v;
            }
        }
    }
}

extern "C" void kernel_launch(void* const* d_in, const int* in_sizes, int n_in,
                              void* d_out, int out_size, void* d_ws, size_t ws_size,
                              hipStream_t stream) {
    const float* x   = (const float*)d_in[0];
    const int*   ei  = (const int*)d_in[1];
    const float* W1l = (const float*)d_in[2];
    const float* b1l = (const float*)d_in[3];
    const float* W1r = (const float*)d_in[4];
    const float* W2l = (const float*)d_in[5];
    const float* b2l = (const float*)d_in[6];
    const float* W2r = (const float*)d_in[7];
    float* out = (float*)d_out;

    const int* src = ei;
    const int* dst = ei + NEDGES;

    // ---- workspace layout ----
    char* ws = (char*)d_ws;
    unsigned short* xe    = (unsigned short*)ws; ws += (size_t)NNODES * 128 * 2;  // 25.6 MB sliced
    unsigned short* he    = (unsigned short*)ws; ws += (size_t)NNODES * 128 * 2;  // 25.6 MB sliced
    unsigned int* sortedSrc = (unsigned int*)ws; ws += (size_t)NEDGES * 4;        // 6.4 MB
    int* rowBeg     = (int*)ws; ws += (size_t)NNODES * 4;
    int* rowEnd     = (int*)ws; ws += (size_t)NNODES * 4;
    int* degCnt     = (int*)ws; ws += (size_t)(NNODES + 1) * 4;  // +1: cursor
    int* cursor     = degCnt + NNODES;
    unsigned short* edgeOrd = (unsigned short*)ws; ws += (size_t)NEDGES * 2;      // 3.2 MB
    uint4* Wf1 = (uint4*)ws; ws += 4096 * 16;   // 64 KB fragment-packed L1 weights
    uint4* Wf2 = (uint4*)ws; ws += 2048 * 16;   // 32 KB fragment-packed L2 weights

    const int gFus = NNODES / 16;               // 6250 blocks x 16 nodes (exact)

    hipMemsetAsync(degCnt, 0, (size_t)(NNODES + 1) * 4, stream);
    prep_kernel<<<GCNT + GENC + GWPK, 256, 0, stream>>>(
        src, dst, degCnt, edgeOrd, (const float4*)x, (uint4*)xe,
        W1l, W1r, W2l, W2r, Wf1, Wf2);
    scan_kernel<<<GSCN, 256, 0, stream>>>(degCnt, cursor, rowBeg, rowEnd);
    scatter_kernel<<<GCNT, 256, 0, stream>>>(src, dst, edgeOrd, rowBeg, sortedSrc);

    // ---- layer 1: aggregate(xe) + GEMM -> he (sliced, encoded, relu) ----
    sage_fused<128, true, true, unsigned short><<<gFus, 256, 0, stream>>>(
        (const uint4*)xe, rowBeg, rowEnd, sortedSrc, Wf1, b1l, he, NNODES);
    // ---- layer 2: aggregate(he) + GEMM -> out (linear f32) ----
    sage_fused<64, false, false, float><<<gFus, 256, 0, stream>>>(
        (const uint4*)he, rowBeg, rowEnd, sortedSrc, Wf2, b2l, out, NNODES);
}

// Round 10
// 260.142 us; speedup vs baseline: 1.3565x; 1.3565x over previous
//
#include <hip/hip_runtime.h>
#include <cstdint>

#define NNODES 100000
#define NEDGES 1600000
#define NBKT   196          // ceil(NNODES / 512); bucket = dst >> 9
#define CAP    9216         // per-bucket capacity: mean 8192 + ~11 sigma
#define BIN_CHUNK 4096
#define GBIN ((NEDGES + BIN_CHUNK - 1) / BIN_CHUNK)   // 391
#define GCVT (NNODES * 16 / 256)                      // 6250 (1 uint4/thread)
#define GWPK 24                                       // weight-pack blocks (6144 thr)

typedef __attribute__((ext_vector_type(8))) __bf16 bf16x8;
typedef __attribute__((ext_vector_type(4))) float f32x4;
typedef short v2s __attribute__((ext_vector_type(2)));

__device__ __forceinline__ unsigned short f2bf_rne(float f) {
    unsigned int u = __float_as_uint(f);
    u += 0x7fffu + ((u >> 16) & 1u);
    return (unsigned short)(u >> 16);
}
// involutive monotone map: bf16 float order <-> signed i16 order (per packed half)
__device__ __forceinline__ unsigned encdec(unsigned u) {
    return u ^ (((u & 0x80008000u) >> 15) * 0x7FFFu);
}
__device__ __forceinline__ unsigned pkmax(unsigned a, unsigned b) {
    v2s r = __builtin_elementwise_max(__builtin_bit_cast(v2s, a), __builtin_bit_cast(v2s, b));
    return __builtin_bit_cast(unsigned, r);
}
__device__ __forceinline__ uint4 pkmax4(uint4 a, uint4 b) {
    uint4 r;
    r.x = pkmax(a.x, b.x); r.y = pkmax(a.y, b.y);
    r.z = pkmax(a.z, b.z); r.w = pkmax(a.w, b.w);
    return r;
}

// ===== 2-SLICE layout =====
// Feature matrices [N][128] bf16 stored as 2 slices of 64 channels:
//   uint4 index(slice s, node n, j) = ((size_t)s*N + n)*8 + j,  j in [0,8)

// ---------------- prep: bin edges | encode x | pack weights (one kernel) -----
__global__ __launch_bounds__(256) void prep_kernel(
        const int* __restrict__ src, const int* __restrict__ dst,
        unsigned int* __restrict__ binArr, int* __restrict__ bucketFill,
        const float4* __restrict__ xin, uint4* __restrict__ xeout,
        const float* __restrict__ W1l, const float* __restrict__ W1r,
        const float* __restrict__ W2l, const float* __restrict__ W2r,
        uint4* __restrict__ Wf1, uint4* __restrict__ Wf2, int nE) {
    if (blockIdx.x >= GBIN + GCVT) {
        // ---- weight pack (24 blocks) ----
        int t = (blockIdx.x - GBIN - GCVT) * 256 + threadIdx.x;   // 0..6143
        unsigned short s[8];
        if (t < 4096) {                           // layer 1: BN=128, NT=8
            int h = t >> 11, kt = (t >> 9) & 3, nt = (t >> 6) & 7, lane = t & 63;
            const float* W = h ? W1r : W1l;
            int k0 = kt * 32 + (lane >> 4) * 8;
            int col = nt * 16 + (lane & 15);
#pragma unroll
            for (int jj = 0; jj < 8; ++jj) s[jj] = f2bf_rne(W[(k0 + jj) * 128 + col]);
            uint4 o;
            o.x = (unsigned)s[0] | ((unsigned)s[1] << 16);
            o.y = (unsigned)s[2] | ((unsigned)s[3] << 16);
            o.z = (unsigned)s[4] | ((unsigned)s[5] << 16);
            o.w = (unsigned)s[6] | ((unsigned)s[7] << 16);
            Wf1[t] = o;
        } else {                                  // layer 2: BN=64, NT=4
            int u = t - 4096;                     // 0..2047
            int h = u >> 10, kt = (u >> 8) & 3, nt = (u >> 6) & 3, lane = u & 63;
            const float* W = h ? W2r : W2l;
            int k0 = kt * 32 + (lane >> 4) * 8;
            int col = nt * 16 + (lane & 15);
#pragma unroll
            for (int jj = 0; jj < 8; ++jj) s[jj] = f2bf_rne(W[(k0 + jj) * 64 + col]);
            uint4 o;
            o.x = (unsigned)s[0] | ((unsigned)s[1] << 16);
            o.y = (unsigned)s[2] | ((unsigned)s[3] << 16);
            o.z = (unsigned)s[4] | ((unsigned)s[5] << 16);
            o.w = (unsigned)s[6] | ((unsigned)s[7] << 16);
            Wf2[u] = o;
        }
        return;
    }
    if (blockIdx.x >= GBIN) {
        // ---- encode x into sliced layout ----
        int t = (blockIdx.x - GBIN) * 256 + threadIdx.x;  // 0..1.6M-1 sliced uint4 idx
        int s = t / (NNODES * 8);
        int rem = t - s * (NNODES * 8);
        int n = rem >> 3, j = rem & 7;
        int f = n * 32 + s * 16 + j * 2;                  // float4 idx (ch 64s+8j)
        float4 v0 = xin[f], v1 = xin[f + 1];
        uint4 o;
        o.x = encdec((unsigned)f2bf_rne(v0.x) | ((unsigned)f2bf_rne(v0.y) << 16));
        o.y = encdec((unsigned)f2bf_rne(v0.z) | ((unsigned)f2bf_rne(v0.w) << 16));
        o.z = encdec((unsigned)f2bf_rne(v1.x) | ((unsigned)f2bf_rne(v1.y) << 16));
        o.w = encdec((unsigned)f2bf_rne(v1.z) | ((unsigned)f2bf_rne(v1.w) << 16));
        xeout[t] = o;
        return;
    }
    // ---- bin: entry = (dst&511)<<17 | src; pass-1 ordinal makes pass-2 atomic-free
    __shared__ unsigned int stage[BIN_CHUNK];
    __shared__ unsigned char bof[BIN_CHUNK];
    __shared__ int cnt[256], cstart[256], gbase[256];
    const int tid = threadIdx.x;
    const int blockStart = blockIdx.x * BIN_CHUNK;
    const int chunkN = min(BIN_CHUNK, nE - blockStart);
    cnt[tid] = 0;
    __syncthreads();
    int myd[16], mys[16];
    unsigned short myo[16];
#pragma unroll
    for (int i = 0; i < 16; ++i) {
        int idx = i * 256 + tid;
        if (idx < chunkN) {
            myd[i] = dst[blockStart + idx];
            mys[i] = src[blockStart + idx];
            myo[i] = (unsigned short)atomicAdd(&cnt[myd[i] >> 9], 1);
        }
    }
    __syncthreads();
    int v = cnt[tid];
    for (int off = 1; off < 256; off <<= 1) {
        int add = (tid >= off) ? cnt[tid - off] : 0;
        __syncthreads();
        cnt[tid] += add;
        __syncthreads();
    }
    cstart[tid] = cnt[tid] - v;
    if (tid < NBKT && v > 0) gbase[tid] = atomicAdd(&bucketFill[tid], v);
    __syncthreads();
#pragma unroll
    for (int i = 0; i < 16; ++i) {
        int idx = i * 256 + tid;
        if (idx < chunkN) {
            int b = myd[i] >> 9;
            int p = cstart[b] + (int)myo[i];              // atomic-free placement
            stage[p] = ((unsigned)(myd[i] & 511) << 17) | (unsigned)mys[i];
            bof[p] = (unsigned char)b;
        }
    }
    __syncthreads();
#pragma unroll
    for (int i = 0; i < 16; ++i) {
        int idx = i * 256 + tid;
        if (idx < chunkN) {
            int b = bof[idx];
            int slot = gbase[b] + (idx - cstart[b]);
            if (slot < CAP) binArr[(size_t)b * CAP + slot] = stage[idx];
        }
    }
}

// ---------------- per-bucket CSR build, 1024 threads, atomic-free scatter ----
__global__ __launch_bounds__(1024) void build_csr_kernel(
        const unsigned int* __restrict__ binArr, const int* __restrict__ bucketFill,
        unsigned int* __restrict__ sortedSrc,
        int* __restrict__ rowBeg, int* __restrict__ rowEnd) {
    __shared__ unsigned int stage[CAP];
    __shared__ unsigned short ordv[CAP];
    __shared__ int ncnt[512], nstart[512];
    const int b = blockIdx.x;
    const int t = threadIdx.x;
    const int cnt_b = min(bucketFill[b], CAP);
    if (t < 512) ncnt[t] = 0;
    __syncthreads();
    for (int i = t; i < cnt_b; i += 1024) {
        unsigned int e = binArr[(size_t)b * CAP + i];
        stage[i] = e;
        ordv[i] = (unsigned short)atomicAdd(&ncnt[e >> 17], 1);  // ordinal captured
    }
    __syncthreads();
    int v = (t < 512) ? ncnt[t] : 0;
    for (int off = 1; off < 512; off <<= 1) {
        int add = (t >= off && t < 512) ? ncnt[t - off] : 0;
        __syncthreads();
        if (t < 512) ncnt[t] += add;
        __syncthreads();
    }
    if (t < 512) {
        int start = ncnt[t] - v;
        nstart[t] = start;
        int n = (b << 9) + t;
        if (n < NNODES) {
            rowBeg[n] = b * CAP + start;
            rowEnd[n] = b * CAP + start + v;
        }
    }
    __syncthreads();
    for (int i = t; i < cnt_b; i += 1024) {
        unsigned int e = stage[i];
        sortedSrc[(size_t)b * CAP + nstart[e >> 17] + (int)ordv[i]] = e & 0x1FFFFu;
    }
}

// ---------------- FUSED aggregate + SAGE GEMM (R6-proven structure) ----------
// Block = 16 nodes. Phase 1: 4 waves gather+max (wave = 8 nodes x 1 slice,
// lane k(3b)|j(3b)), 16-deep prologue + masked tail; result -> LDS [16][17].
// Phase 2: one barrier, 16-row MFMA GEMM (agg@Wl + root@Wr), bias(+relu), write.
template<int BN, bool RELU, bool ENCOUT, typename OutT>
__global__ __launch_bounds__(256) void sage_fused(
        const uint4* __restrict__ xsl,          // sliced encoded features
        const int* __restrict__ rowBeg,
        const int* __restrict__ rowEnd,
        const unsigned int* __restrict__ sortedSrc,
        const uint4* __restrict__ Wf,           // fragment-packed weights
        const float* __restrict__ bias,         // [BN] f32
        OutT* __restrict__ C,                   // ENCOUT: sliced bf16; else [M][BN] f32
        int nN) {
    constexpr int NT = BN / 16;                 // packed column tiles (8 or 4)
    constexpr int NTW = BN / 64;                // column tiles per wave (2 or 1)
    __shared__ uint4 lds[16][17];               // +1 pad: row stride 272B
    const int wv   = threadIdx.x >> 6;
    const int lane = threadIdx.x & 63;
    const int n0   = blockIdx.x * 16;           // grid exact: 6250*16 == NNODES

    // ---------- phase 1: aggregation ----------
    {
        const int s  = wv & 1;                  // slice
        const int nh = wv >> 1;                 // node half
        const int k  = lane >> 3;               // node within half
        const int j  = lane & 7;                // uint4 within 128B slice row
        const int kb = k << 3;
        const int n  = n0 + nh * 8 + k;
        const size_t srow = (size_t)s * nN;

        const int beg = rowBeg[n], end = rowEnd[n];
        const int m = end - beg;

        int maxm = m;
        maxm = max(maxm, __shfl_xor(maxm, 8));
        maxm = max(maxm, __shfl_xor(maxm, 16));
        maxm = max(maxm, __shfl_xor(maxm, 32));

        int idv0 = 0, idv1 = 0;
        if (m > 0) {
            idv0 = (int)sortedSrc[min(beg + j,     end - 1)];
            idv1 = (int)sortedSrc[min(beg + 8 + j, end - 1)];
        }
        int a0 = __shfl(idv0, kb | 0), a1 = __shfl(idv0, kb | 1);
        int a2 = __shfl(idv0, kb | 2), a3 = __shfl(idv0, kb | 3);
        int a4 = __shfl(idv0, kb | 4), a5 = __shfl(idv0, kb | 5);
        int a6 = __shfl(idv0, kb | 6), a7 = __shfl(idv0, kb | 7);
        int b0 = __shfl(idv1, kb | 0), b1 = __shfl(idv1, kb | 1);
        int b2 = __shfl(idv1, kb | 2), b3 = __shfl(idv1, kb | 3);
        int b4 = __shfl(idv1, kb | 4), b5 = __shfl(idv1, kb | 5);
        int b6 = __shfl(idv1, kb | 6), b7 = __shfl(idv1, kb | 7);
        uint4 q0  = xsl[(srow + a0) * 8 + j];
        uint4 q1  = xsl[(srow + a1) * 8 + j];
        uint4 q2  = xsl[(srow + a2) * 8 + j];
        uint4 q3  = xsl[(srow + a3) * 8 + j];
        uint4 q4  = xsl[(srow + a4) * 8 + j];
        uint4 q5  = xsl[(srow + a5) * 8 + j];
        uint4 q6  = xsl[(srow + a6) * 8 + j];
        uint4 q7  = xsl[(srow + a7) * 8 + j];
        uint4 q8  = xsl[(srow + b0) * 8 + j];
        uint4 q9  = xsl[(srow + b1) * 8 + j];
        uint4 q10 = xsl[(srow + b2) * 8 + j];
        uint4 q11 = xsl[(srow + b3) * 8 + j];
        uint4 q12 = xsl[(srow + b4) * 8 + j];
        uint4 q13 = xsl[(srow + b5) * 8 + j];
        uint4 q14 = xsl[(srow + b6) * 8 + j];
        uint4 q15 = xsl[(srow + b7) * 8 + j];
        uint4 accA = pkmax4(pkmax4(pkmax4(q0, q1), pkmax4(q2, q3)),
                            pkmax4(pkmax4(q4, q5), pkmax4(q6, q7)));
        uint4 accB = pkmax4(pkmax4(pkmax4(q8, q9), pkmax4(q10, q11)),
                            pkmax4(pkmax4(q12, q13), pkmax4(q14, q15)));
        uint4 acc = pkmax4(accA, accB);

        for (int e0 = 16; e0 < maxm; e0 += 8) {
            if (e0 < m) {
                int idt = (int)sortedSrc[min(beg + e0 + j, end - 1)];
                int t0 = __shfl(idt, kb | 0), t1 = __shfl(idt, kb | 1);
                int t2 = __shfl(idt, kb | 2), t3 = __shfl(idt, kb | 3);
                int t4 = __shfl(idt, kb | 4), t5 = __shfl(idt, kb | 5);
                int t6 = __shfl(idt, kb | 6), t7 = __shfl(idt, kb | 7);
                uint4 u0 = xsl[(srow + t0) * 8 + j];
                uint4 u1 = xsl[(srow + t1) * 8 + j];
                uint4 u2 = xsl[(srow + t2) * 8 + j];
                uint4 u3 = xsl[(srow + t3) * 8 + j];
                uint4 u4 = xsl[(srow + t4) * 8 + j];
                uint4 u5 = xsl[(srow + t5) * 8 + j];
                uint4 u6 = xsl[(srow + t6) * 8 + j];
                uint4 u7 = xsl[(srow + t7) * 8 + j];
                acc = pkmax4(acc, pkmax4(pkmax4(pkmax4(u0, u1), pkmax4(u2, u3)),
                                         pkmax4(pkmax4(u4, u5), pkmax4(u6, u7))));
            }
        }

        uint4 o;
        if (m > 0) { o = acc; }
        else       { o.x = o.y = o.z = o.w = 0u; }   // enc(0)==0
        lds[nh * 8 + k][s * 8 + j] = o;
    }
    __syncthreads();

    // ---------- phase 2: GEMM (16 rows x BN) ----------
    const int quad = lane >> 4;
    const int mrow = lane & 15;
    const int r    = n0 + mrow;                 // root row (always < nN)

    f32x4 acc[NTW];
#pragma unroll
    for (int t = 0; t < NTW; ++t) acc[t] = (f32x4){0.f, 0.f, 0.f, 0.f};

#pragma unroll
    for (int kt = 0; kt < 4; ++kt) {
        const int q = kt * 4 + quad;            // uint4 idx: channels q*8..q*8+7
        uint4 ta = lds[mrow][q];
        uint4 tr = xsl[((size_t)(q >> 3) * nN + r) * 8 + (q & 7)];
        ta.x = encdec(ta.x); ta.y = encdec(ta.y); ta.z = encdec(ta.z); ta.w = encdec(ta.w);
        tr.x = encdec(tr.x); tr.y = encdec(tr.y); tr.z = encdec(tr.z); tr.w = encdec(tr.w);
        bf16x8 aa = __builtin_bit_cast(bf16x8, ta);
        bf16x8 ar = __builtin_bit_cast(bf16x8, tr);
#pragma unroll
        for (int t = 0; t < NTW; ++t) {
            const int ct = wv * NTW + t;        // global column tile
            bf16x8 wb0 = __builtin_bit_cast(bf16x8, Wf[(kt * NT + ct) * 64 + lane]);
            acc[t] = __builtin_amdgcn_mfma_f32_16x16x32_bf16(aa, wb0, acc[t], 0, 0, 0);
            bf16x8 wb1 = __builtin_bit_cast(bf16x8, Wf[((4 + kt) * NT + ct) * 64 + lane]);
            acc[t] = __builtin_amdgcn_mfma_f32_16x16x32_bf16(ar, wb1, acc[t], 0, 0, 0);
        }
    }

    // epilogue: D layout col=mrow (within tile), row=quad*4+reg
#pragma unroll
    for (int t = 0; t < NTW; ++t) {
        const int col = (wv * NTW + t) * 16 + mrow;
        const float bv = bias[col];
#pragma unroll
        for (int rr = 0; rr < 4; ++rr) {
            const int grow = n0 + quad * 4 + rr;
            float v = acc[t][rr] + bv;
            if (RELU) v = fmaxf(v, 0.0f);
            if constexpr (ENCOUT) {
                unsigned u = f2bf_rne(v);
                u ^= ((u >> 15) & 1u) * 0x7FFFu;   // encode for next layer
                // sliced write: slice=col>>6, within-slice ch=col&63
                C[((size_t)(col >> 6) * nN + grow) * 64 + (col & 63)] = (OutT)u;
            } else {
                C[(size_t)grow * BN + col] = (OutT)v;
            }
        }
    }
}

extern "C" void kernel_launch(void* const* d_in, const int* in_sizes, int n_in,
                              void* d_out, int out_size, void* d_ws, size_t ws_size,
                              hipStream_t stream) {
    const float* x   = (const float*)d_in[0];
    const int*   ei  = (const int*)d_in[1];
    const float* W1l = (const float*)d_in[2];
    const float* b1l = (const float*)d_in[3];
    const float* W1r = (const float*)d_in[4];
    const float* W2l = (const float*)d_in[5];
    const float* b2l = (const float*)d_in[6];
    const float* W2r = (const float*)d_in[7];
    float* out = (float*)d_out;

    const int* src = ei;
    const int* dst = ei + NEDGES;

    // ---- workspace layout ----
    char* ws = (char*)d_ws;
    unsigned short* xe    = (unsigned short*)ws; ws += (size_t)NNODES * 128 * 2;  // 25.6 MB sliced
    unsigned short* he    = (unsigned short*)ws; ws += (size_t)NNODES * 128 * 2;  // 25.6 MB sliced
    unsigned int* binArr    = (unsigned int*)ws; ws += (size_t)NBKT * CAP * 4;    // 7.2 MB
    unsigned int* sortedSrc = (unsigned int*)ws; ws += (size_t)NBKT * CAP * 4;    // 7.2 MB
    int* rowBeg     = (int*)ws; ws += (size_t)NNODES * 4;
    int* rowEnd     = (int*)ws; ws += (size_t)NNODES * 4;
    int* bucketFill = (int*)ws; ws += 256 * 4;
    uint4* Wf1 = (uint4*)ws; ws += 4096 * 16;   // 64 KB fragment-packed L1 weights
    uint4* Wf2 = (uint4*)ws; ws += 2048 * 16;   // 32 KB fragment-packed L2 weights

    const int gFus = NNODES / 16;               // 6250 blocks x 16 nodes (exact)

    hipMemsetAsync(bucketFill, 0, 256 * sizeof(int), stream);
    prep_kernel<<<GBIN + GCVT + GWPK, 256, 0, stream>>>(
        src, dst, binArr, bucketFill, (const float4*)x, (uint4*)xe,
        W1l, W1r, W2l, W2r, Wf1, Wf2, NEDGES);
    build_csr_kernel<<<NBKT, 1024, 0, stream>>>(binArr, bucketFill, sortedSrc, rowBeg, rowEnd);

    // ---- layer 1: aggregate(xe) + GEMM -> he (sliced, encoded, relu) ----
    sage_fused<128, true, true, unsigned short><<<gFus, 256, 0, stream>>>(
        (const uint4*)xe, rowBeg, rowEnd, sortedSrc, Wf1, b1l, he, NNODES);
    // ---- layer 2: aggregate(he) + GEMM -> out (linear f32) ----
    sage_fused<64, false, false, float><<<gFus, 256, 0, stream>>>(
        (const uint4*)he, rowBeg, rowEnd, sortedSrc, Wf2, b2l, out, NNODES);
}